// Round 10
// baseline (125.463 us; speedup 1.0000x reference)
//
#include <hip/hip_runtime.h>
#include <stdint.h>

#define N_RAYS  16384
#define T_STEPS 128
#define RPW   16            // rays per wave (= per block)
#define WAVES 8             // waves per block; wave w owns t in [16w, 16w+16)
#define TSEG  16

typedef _Float16 half8  __attribute__((ext_vector_type(8)));
typedef _Float16 half4  __attribute__((ext_vector_type(4)));
typedef __fp16   fp16x2 __attribute__((ext_vector_type(2)));
typedef float    float4_ __attribute__((ext_vector_type(4)));

#define LOG2E 1.4426950408889634f
// log2(log2(e)) for the sigma-prescale fold
#define LOG2_LOG2E 0.5287663729448977f

__device__ __forceinline__ uint32_t pk(float a, float b) {
    fp16x2 h = __builtin_amdgcn_cvt_pkrtz(a, b);
    return __builtin_bit_cast(uint32_t, h);
}
// pack two floats -> f16x2 dword, then packed relu (v_pk_max_f16)
__device__ __forceinline__ uint32_t pkr(float a, float b) {
    fp16x2 h = __builtin_amdgcn_cvt_pkrtz(a, b);
    fp16x2 z = {(__fp16)0.f, (__fp16)0.f};
    fp16x2 m = __builtin_elementwise_max(h, z);
    return __builtin_bit_cast(uint32_t, m);
}

// ---------------------------------------------------------------------------
// Single fused kernel: per-wave setup gathers the MFMA weight fragments
// DIRECTLY from the global weight arrays (register gather, no LDS image, no
// barrier, no prep dispatch). The b2 feature-bias is applied as the L2 MFMA
// C-initializer (exact f32) instead of being pre-folded into the C1 init --
// this kills the 15-term cconst fold that made round 8's fused prologue slow.
// Evidence trail: round-8 LDS-prologue fusion cost +5.5us; prep as separate
// dispatch cost ~2-4us + a launch gap. This variant removes both.
// launch_bounds min-waves 4 (VGPR cap 128): allocator lands ~60 VGPR; min=8
// caused catastrophic spill (VGPR=32, 1.3 GB scratch, 332 us). Don't tighten.
// ---------------------------------------------------------------------------
__global__ __launch_bounds__(512, 4)
void render_kernel(const float* __restrict__ rays_o, const float* __restrict__ rays_d,
                   const float* __restrict__ tnoise, const float* __restrict__ aabb,
                   const float* __restrict__ W1, const float* __restrict__ b1,
                   const float* __restrict__ W2, const float* __restrict__ b2,
                   const float* __restrict__ Wc1, const float* __restrict__ bc1,
                   const float* __restrict__ Wc2, const float* __restrict__ bc2,
                   float* __restrict__ out) {
    __shared__ float sComb[WAVES][RPW][4];   // [0]=trans_end, [1..3]=rgb acc

    const int tid  = threadIdx.x;
    const int wv   = tid >> 6;
    const int lane = tid & 63;
    const int m    = lane & 15;       // ray within block / sample col
    const int q    = lane >> 4;       // quad
    const int r    = blockIdx.x * RPW + m;

    const bool q0 = (q == 0), q1 = (q == 1);

    // ---- weight fragments -> registers, gathered straight from global ----
    // fW1: A-frag for L1 (enc-permuted, b1 folded into slot j=7 on q1)
    half8 fW1[4];
    #pragma unroll
    for (int tau = 0; tau < 4; ++tau) {
        int n = tau * 16 + m;
        float v0 = W1[(3 + 6 * q + 0) * 64 + n];
        float v1 = W1[(3 + 6 * q + 1) * 64 + n];
        float v2 = W1[(3 + 6 * q + 2) * 64 + n];
        float v3 = W1[(3 + 6 * q + 3) * 64 + n];
        float v4 = W1[(3 + 6 * q + 4) * 64 + n];
        float v5 = W1[(3 + 6 * q + 5) * 64 + n];
        float v6 = q0 ? W1[0 * 64 + n] : (q1 ? W1[2 * 64 + n] : 0.f);
        float v7 = q0 ? W1[1 * 64 + n] : (q1 ? b1[n] : 0.f);
        union { uint32_t u[4]; half8 h; } t;
        t.u[0] = pk(v0, v1); t.u[1] = pk(v2, v3);
        t.u[2] = pk(v4, v5); t.u[3] = pk(v6, v7);
        fW1[tau] = t.h;
    }
    // fW2: K=16 A-frag tiles A[row=m][k=4q+j]; row 0 (sigma) scaled by log2e
    half4 fW2[4];
    #pragma unroll
    for (int tau = 0; tau < 4; ++tau) {
        float v[4];
        #pragma unroll
        for (int j = 0; j < 4; ++j) {
            int k = tau * 16 + 4 * q + j;
            v[j] = W2[k * 16 + m];
        }
        if (m == 0) { v[0] *= LOG2E; v[1] *= LOG2E; v[2] *= LOG2E; v[3] *= LOG2E; }
        union { uint32_t u[2]; half4 h; } t;
        t.u[0] = pk(v[0], v[1]); t.u[1] = pk(v[2], v[3]);
        fW2[tau] = t.h;
    }
    // fWc1: K=16 A-frag tiles; k=0 is the dead sigma slot (weight 0)
    half4 fWc1[4];
    #pragma unroll
    for (int tau = 0; tau < 4; ++tau) {
        int n2 = tau * 16 + m;
        float v[4];
        #pragma unroll
        for (int j = 0; j < 4; ++j) {
            int k = 4 * q + j;
            v[j] = (k == 0) ? 0.f : Wc1[(k - 1) * 64 + n2];
        }
        union { uint32_t u[2]; half4 h; } t;
        t.u[0] = pk(v[0], v[1]); t.u[1] = pk(v[2], v[3]);
        fWc1[tau] = t.h;
    }
    // fWc2: K=16 A-frag tiles, channel-replicated rows (row mm -> ch mm>>2),
    // scaled by log2e so the sigmoid is a bare exp2
    half4 fWc2[4];
    #pragma unroll
    for (int tau = 0; tau < 4; ++tau) {
        float v[4];
        #pragma unroll
        for (int j = 0; j < 4; ++j) {
            int k = tau * 16 + 4 * q + j;
            v[j] = (m < 12) ? Wc2[k * 3 + (m >> 2)] * LOG2E : 0.f;
        }
        union { uint32_t u[2]; half4 h; } t;
        t.u[0] = pk(v[0], v[1]); t.u[1] = pk(v[2], v[3]);
        fWc2[tau] = t.h;
    }
    // b2 as L2 C-initializer (C row = 4q+reg); row 0 carries log2e
    float4_ b2v;
    #pragma unroll
    for (int j = 0; j < 4; ++j) b2v[j] = b2[4 * q + j];
    if (q0) b2v[0] *= LOG2E;
    // bc2 as C2 C-initializer: channel q for q<3 (replicated rows), x log2e
    float bb = (q < 3) ? bc2[q] * LOG2E : 0.0f;
    const float4_ binit = {bb, bb, bb, bb};

    // per-ray setup
    float o0 = rays_o[r * 3 + 0], o1 = rays_o[r * 3 + 1], o2 = rays_o[r * 3 + 2];
    float d0 = rays_d[r * 3 + 0], d1 = rays_d[r * 3 + 1], d2 = rays_d[r * 3 + 2];
    float a00 = aabb[0], a01 = aabb[1], a02 = aabb[2];
    float a10 = aabb[3], a11 = aabb[4], a12 = aabb[5];

    float i0 = 1.0f / d0, i1 = 1.0f / d1, i2 = 1.0f / d2;
    float u0 = (a00 - o0) * i0, v0 = (a10 - o0) * i0;
    float u1 = (a01 - o1) * i1, v1 = (a11 - o1) * i1;
    float u2 = (a02 - o2) * i2, v2 = (a12 - o2) * i2;
    float tnear = fmaxf(fmaxf(fmaxf(fminf(u0, v0), fminf(u1, v1)), fminf(u2, v2)), 0.0f);
    float tfar  = fminf(fminf(fmaxf(u0, v0), fmaxf(u1, v1)), fmaxf(u2, v2));
    bool active = (tfar > tnear);
    float dt = tfar - tnear;
    float dt128 = dt * (1.0f / 128.0f);

    float dn  = sqrtf(d0 * d0 + d1 * d1 + d2 * d2);
    float idn = 1.0f / dn;
    // sigma bias in log2 domain (b2[0] now lives in the L2 accumulator)
    const float s0r = LOG2_LOG2E + __builtin_amdgcn_logf(dn);
    const float c0sh = 0.28209479177387814f;
    const float c1sh = 0.4886025119029199f;
    float y1 = c1sh * d1 * idn, y2 = c1sh * d2 * idn, y3 = c1sh * d0 * idn;

    // C1 C-initializer (per-ray): cv[n] = bc1[n] + c0*W15[n] + y.W16..18[n]
    // (b2 feat-bias no longer folded here -- it rides the L2 accumulator)
    float4_ cv[4];
    #pragma unroll
    for (int tau = 0; tau < 4; ++tau) {
        #pragma unroll
        for (int reg = 0; reg < 4; ++reg) {
            int n = tau * 16 + 4 * q + reg;
            float c = bc1[n];
            c = fmaf(c0sh, Wc1[15 * 64 + n], c);
            c = fmaf(y1,   Wc1[16 * 64 + n], c);
            c = fmaf(y2,   Wc1[17 * 64 + n], c);
            c = fmaf(y3,   Wc1[18 * 64 + n], c);
            cv[tau][reg] = c;
        }
    }

    // xn in revolutions domain, ray-affine prefolded: xr = ts*k + b
    float qs = 0.5f * (float)(1 << q);
    float sc0 = 2.0f / (a10 - a00), of0 = -a00 * sc0 - 1.0f;
    float sc1 = 2.0f / (a11 - a01), of1 = -a01 * sc1 - 1.0f;
    float sc2 = 2.0f / (a12 - a02), of2 = -a02 * sc2 - 1.0f;
    float kq0 = d0 * (sc0 * qs), bq0 = fmaf(o0, sc0 * qs, of0 * qs);
    float kq1 = d1 * (sc1 * qs), bq1 = fmaf(o1, sc1 * qs, of1 * qs);
    float kq2 = d2 * (sc2 * qs), bq2 = fmaf(o2, sc2 * qs, of2 * qs);

    const float4_ z4 = {0.f, 0.f, 0.f, 0.f};
    const float c6 = q0 ? 2.0f : (q1 ? 1.0f : 0.0f);
    // e7 = fma(xr1, c7a, c7b): 2*xr1 on q0, const 1 on q1, 0 elsewhere
    const float c7a = q0 ? 2.0f : 0.0f;
    const float c7b = q1 ? 1.0f : 0.0f;

    float trans = 1.0f;
    float cacc = 0.0f;     // this lane's channel accumulator (q<3 meaningful)

    const int tbase = wv * TSEG;
    float nA = tnoise[(tbase + 0) * N_RAYS + r];
    float nB = tnoise[(tbase + 1) * N_RAYS + r];

    #pragma unroll 1
    for (int tt = 0; tt < TSEG; tt += 2) {
        const int t0 = tbase + tt, t1 = t0 + 1;
        // clamped prefetch: the clamp only hits samples whose value is dead
        int ic = t0 + 2; if (ic > T_STEPS - 1) ic = T_STEPS - 1;
        int id = t0 + 3; if (id > T_STEPS - 1) id = T_STEPS - 1;
        float nC = tnoise[ic * N_RAYS + r];
        float nD = tnoise[id * N_RAYS + r];
        float ts0 = fmaf((float)t0 + nA, dt128, tnear);
        float ts1 = fmaf((float)t1 + nB, dt128, tnear);
        float ts2 = fmaf((float)(t0 + 2) + nC, dt128, tnear);
        float tsP[2] = {ts0, ts1};
        float deltaP[2];
        deltaP[0] = ts1 - ts0;
        deltaP[1] = (t1 < T_STEPS - 1) ? (ts2 - ts1) : fmaf(tfar, 10.0f, -ts1);
        nA = nC; nB = nD;

        float dhx[2];      // sigma logit (log2 domain), broadcast to ALL lanes
        float4_ rgbP[2];   // reg0 = this quad's channel logit (log2 domain)

        // ---- per-phase fully in-register MLP: posenc -> L1 -> L2 -> C1 -> C2
        #pragma unroll
        for (int p = 0; p < 2; ++p) {
            float xr0 = fmaf(tsP[p], kq0, bq0);
            float xr1 = fmaf(tsP[p], kq1, bq1);
            float xr2 = fmaf(tsP[p], kq2, bq2);
            float s0 = __builtin_amdgcn_sinf(xr0);
            float s1 = __builtin_amdgcn_sinf(xr1);
            float s2 = __builtin_amdgcn_sinf(xr2);
            float cA = __builtin_amdgcn_cosf(xr0);
            float cB = __builtin_amdgcn_cosf(xr1);
            float cC = __builtin_amdgcn_cosf(xr2);
            float e6 = c6 * (q0 ? xr0 : xr2);
            float e7 = fmaf(xr1, c7a, c7b);
            union { uint32_t u[4]; half8 h; } xf_;
            xf_.u[0] = pk(s0, s1); xf_.u[1] = pk(s2, cA);
            xf_.u[2] = pk(cB, cC); xf_.u[3] = pk(e6, e7);
            half8 xf = xf_.h;

            // L1: 64 hidden x 16 rays, K=32 (enc padded)
            float4_ h0 = __builtin_amdgcn_mfma_f32_16x16x32_f16(fW1[0], xf, z4, 0, 0, 0);
            float4_ h1 = __builtin_amdgcn_mfma_f32_16x16x32_f16(fW1[1], xf, z4, 0, 0, 0);
            float4_ h2 = __builtin_amdgcn_mfma_f32_16x16x32_f16(fW1[2], xf, z4, 0, 0, 0);
            float4_ h3 = __builtin_amdgcn_mfma_f32_16x16x32_f16(fW1[3], xf, z4, 0, 0, 0);

            // relu-pack each h C-frag; C rows 4q+reg == K16 B-frag k=4q+j
            union { uint32_t u[2]; half4 h; } hb0_, hb1_, hb2_, hb3_;
            hb0_.u[0] = pkr(h0.x, h0.y); hb0_.u[1] = pkr(h0.z, h0.w);
            hb1_.u[0] = pkr(h1.x, h1.y); hb1_.u[1] = pkr(h1.z, h1.w);
            hb2_.u[0] = pkr(h2.x, h2.y); hb2_.u[1] = pkr(h2.z, h2.w);
            hb3_.u[0] = pkr(h3.x, h3.y); hb3_.u[1] = pkr(h3.z, h3.w);

            // L2: dh = b2 + sum_tau W2_tau . relu(h_tau); acc starts at b2
            float4_ dh = __builtin_amdgcn_mfma_f32_16x16x16f16(fW2[0], hb0_.h, b2v, 0, 0, 0);
            dh = __builtin_amdgcn_mfma_f32_16x16x16f16(fW2[1], hb1_.h, dh, 0, 0, 0);
            dh = __builtin_amdgcn_mfma_f32_16x16x16f16(fW2[2], hb2_.h, dh, 0, 0, 0);
            dh = __builtin_amdgcn_mfma_f32_16x16x16f16(fW2[3], hb3_.h, dh, 0, 0, 0);

            // broadcast sigma logit (row 0, lives on lane (0,m)) to all lanes;
            // issued here so the bpermute latency hides under C1/C2 MFMAs
            dhx[p] = __shfl(dh.x, m, 64);

            // dh C-layout == 16x16x16 B-layout: feed C1 directly
            union { uint32_t u[2]; half4 h; } fb_;
            fb_.u[0] = pk(dh.x, dh.y); fb_.u[1] = pk(dh.z, dh.w);
            half4 fb = fb_.h;

            float4_ t0v = __builtin_amdgcn_mfma_f32_16x16x16f16(fWc1[0], fb, cv[0], 0, 0, 0);
            float4_ t1v = __builtin_amdgcn_mfma_f32_16x16x16f16(fWc1[1], fb, cv[1], 0, 0, 0);
            float4_ t2v = __builtin_amdgcn_mfma_f32_16x16x16f16(fWc1[2], fb, cv[2], 0, 0, 0);
            float4_ t3v = __builtin_amdgcn_mfma_f32_16x16x16f16(fWc1[3], fb, cv[3], 0, 0, 0);

            // relu-pack HC C-frags; feed C2 as 4 K=16 tiles, single acc chain
            union { uint32_t u[2]; half4 h; } cb0_, cb1_, cb2_, cb3_;
            cb0_.u[0] = pkr(t0v.x, t0v.y); cb0_.u[1] = pkr(t0v.z, t0v.w);
            cb1_.u[0] = pkr(t1v.x, t1v.y); cb1_.u[1] = pkr(t1v.z, t1v.w);
            cb2_.u[0] = pkr(t2v.x, t2v.y); cb2_.u[1] = pkr(t2v.z, t2v.w);
            cb3_.u[0] = pkr(t3v.x, t3v.y); cb3_.u[1] = pkr(t3v.z, t3v.w);

            float4_ rr4 = __builtin_amdgcn_mfma_f32_16x16x16f16(fWc2[0], cb0_.h, binit, 0, 0, 0);
            rr4 = __builtin_amdgcn_mfma_f32_16x16x16f16(fWc2[1], cb1_.h, rr4, 0, 0, 0);
            rr4 = __builtin_amdgcn_mfma_f32_16x16x16f16(fWc2[2], cb2_.h, rr4, 0, 0, 0);
            rr4 = __builtin_amdgcn_mfma_f32_16x16x16f16(fWc2[3], cb3_.h, rr4, 0, 0, 0);
            rgbP[p] = rr4;
        }

        // ---- TAIL: wave-uniform scan, exp2-domain, 2-op telescoped update ----
        #pragma unroll
        for (int p = 0; p < 2; ++p) {
            float sg = __builtin_amdgcn_exp2f(dhx[p] + s0r);   // log2e*dn*sigma
            float sd = sg * deltaP[p];
            float e  = __builtin_amdgcn_exp2f(-sd);
            float s  = __builtin_amdgcn_rcpf(1.0f + __builtin_amdgcn_exp2f(-rgbP[p].x));
            float tn = trans * e;
            cacc = fmaf(trans - tn, s, cacc);
            trans = tn;
        }
    }

    if (q == 3) sComb[wv][m][0] = trans;       // trans uniform across quads
    else        sComb[wv][m][1 + q] = cacc;
    __syncthreads();

    // cross-segment combine: pure multiply chain, alpha_map telescopes
    if (tid < RPW) {
        float P = 1.0f, C0 = 0.0f, C1 = 0.0f, C2 = 0.0f;
        #pragma unroll
        for (int s = 0; s < WAVES; ++s) {
            C0 = fmaf(P, sComb[s][tid][1], C0);
            C1 = fmaf(P, sComb[s][tid][2], C1);
            C2 = fmaf(P, sComb[s][tid][3], C2);
            P *= sComb[s][tid][0];
        }
        float act = active ? 1.0f : 0.0f;
        const int rg = blockIdx.x * RPW + tid;
        out[rg * 4 + 0] = C0 * act;
        out[rg * 4 + 1] = C1 * act;
        out[rg * 4 + 2] = C2 * act;
        out[rg * 4 + 3] = (1.0f - P) * act;
    }
}

extern "C" void kernel_launch(void* const* d_in, const int* in_sizes, int n_in,
                              void* d_out, int out_size, void* d_ws, size_t ws_size,
                              hipStream_t stream) {
    const float* rays_o = (const float*)d_in[0];
    const float* rays_d = (const float*)d_in[1];
    const float* tnoise = (const float*)d_in[2];
    const float* aabb   = (const float*)d_in[3];
    const float* W1  = (const float*)d_in[4];
    const float* b1  = (const float*)d_in[5];
    const float* W2  = (const float*)d_in[6];
    const float* b2  = (const float*)d_in[7];
    const float* Wc1 = (const float*)d_in[8];
    const float* bc1 = (const float*)d_in[9];
    const float* Wc2 = (const float*)d_in[10];
    const float* bc2 = (const float*)d_in[11];

    dim3 grid(N_RAYS / RPW);   // 1024 blocks
    dim3 block(WAVES * 64);    // 512 threads, 8 waves
    render_kernel<<<grid, block, 0, stream>>>(rays_o, rays_d, tnoise, aabb,
                                              W1, b1, W2, b2, Wc1, bc1, Wc2, bc2,
                                              (float*)d_out);
}

// Round 11
// 115.053 us; speedup vs baseline: 1.0905x; 1.0905x over previous
//
#include <hip/hip_runtime.h>
#include <stdint.h>

#define N_RAYS  16384
#define T_STEPS 128
#define RPW   16            // rays per wave (= per block)
#define WAVES 8             // waves per block; wave w owns t in [16w, 16w+16)
#define TSEG  16

typedef _Float16 half8  __attribute__((ext_vector_type(8)));
typedef _Float16 half4  __attribute__((ext_vector_type(4)));
typedef __fp16   fp16x2 __attribute__((ext_vector_type(2)));
typedef float    float4_ __attribute__((ext_vector_type(4)));

#define LOG2E 1.4426950408889634f
// log2(log2(e)) for the sigma-prescale fold
#define LOG2_LOG2E 0.5287663729448977f

// ws layout, half indices:
//   W1 x32 A-frag half8 tiles   [0, 2048)
//   W2  K16 A-frag half4 tiles  [2048, 3072)  (row 0 scaled by log2e)
//   Wc2 K16 A-frag half4 tiles  [3072, 4096)  (channel-replicated, x log2e)
//   Wc1 K16 A-frag half4 tiles  [4096, 5120)
//   f32 region at float index 3072 (byte 12288)
#define H8_W1    0
#define H_W2K16  2048
#define H_WC2K16 3072
#define H_WC1K16 4096
#define F32_CV   3072        // 5 x 64: Wc1 rows 15,16,17,18 then cconst
#define F32_BC2  3392        // 16 floats (bc2 channel-replicated, x log2e)
#define F32_S0   3408        // b2[0]*log2e + log2(log2e)

__device__ __forceinline__ uint32_t pk(float a, float b) {
    fp16x2 h = __builtin_amdgcn_cvt_pkrtz(a, b);
    return __builtin_bit_cast(uint32_t, h);
}
// pack two floats -> f16x2 dword, then packed relu (v_pk_max_f16)
__device__ __forceinline__ uint32_t pkr(float a, float b) {
    fp16x2 h = __builtin_amdgcn_cvt_pkrtz(a, b);
    fp16x2 z = {(__fp16)0.f, (__fp16)0.f};
    fp16x2 m = __builtin_elementwise_max(h, z);
    return __builtin_bit_cast(uint32_t, m);
}

// ---------------------------------------------------------------------------
// prep. 17 blocks x 64 threads; blockIdx = fragment group.
// W2 / Wc1 / Wc2 are K=16 A-frag tiles: A[row=mm][k=4q+j].
// exp2-domain folds: W2 row 0 (sigma logit), Wc2, bc2 and b2[0] carry log2e.
// FUSION IS SETTLED (rounds 8/10): LDS-prologue fusion +5.5us, per-wave
// global gather +10us, split prep ~2-4us. Keep the split.
// ---------------------------------------------------------------------------
__global__ void prep_weights(const float* __restrict__ W1, const float* __restrict__ b1,
                             const float* __restrict__ W2, const float* __restrict__ b2,
                             const float* __restrict__ Wc1, const float* __restrict__ bc1,
                             const float* __restrict__ Wc2, const float* __restrict__ bc2,
                             void* __restrict__ ws) {
    _Float16* wh = (_Float16*)ws;
    float*    wf = (float*)ws;
    int frag = blockIdx.x;
    int lane = threadIdx.x;
    int mm = lane & 15, q = lane >> 4;
    if (frag < 4) {                       // W1^T tiles (enc-permuted, b1 folded)
        int tau = frag;
        int n = tau * 16 + mm;
        for (int j = 0; j < 8; ++j) {
            float w;
            if (j < 6)      w = W1[(3 + 6 * q + j) * 64 + n];
            else if (j == 6) w = (q == 0) ? W1[0 * 64 + n] : (q == 1) ? W1[2 * 64 + n] : 0.f;
            else             w = (q == 0) ? W1[1 * 64 + n] : (q == 1) ? b1[n] : 0.f;
            wh[(H8_W1 + tau * 64 + lane) * 8 + j] = (_Float16)w;
        }
    } else if (frag < 8) {                // W2 as K=16 A-frag tiles (row0 x log2e)
        int tau = frag - 4;               // A[n=mm][k=4q+j], global k = 16 tau + 4q + j
        for (int j = 0; j < 4; ++j) {
            int k = tau * 16 + 4 * q + j;
            float v = W2[k * 16 + mm];
            if (mm == 0) v *= LOG2E;
            wh[H_W2K16 + (tau * 64 + lane) * 4 + j] = (_Float16)v;
        }
    } else if (frag < 12) {               // Wc1 as K=16 A-frag tiles
        int tau = frag - 8;               // A[n'=16 tau+mm][k=4q+j]; k=0 -> dead sigma slot
        int n2 = tau * 16 + mm;
        for (int j = 0; j < 4; ++j) {
            int k = 4 * q + j;
            float w = (k == 0) ? 0.f : Wc1[(k - 1) * 64 + n2];
            wh[H_WC1K16 + (tau * 64 + lane) * 4 + j] = (_Float16)w;
        }
    } else if (frag < 16) {               // Wc2 K=16 tiles, channel-replicated, x log2e
        int tau = frag - 12;              // A[n=mm][k=16 tau+4q+j]; row mm -> channel mm>>2
        for (int j = 0; j < 4; ++j) {
            int k = tau * 16 + 4 * q + j;
            wh[H_WC2K16 + (tau * 64 + lane) * 4 + j] =
                (_Float16)((mm < 12) ? Wc2[k * 3 + (mm >> 2)] * LOG2E : 0.f);
        }
    } else {                              // f32 constant tables
        int n = lane;
        wf[F32_CV + 0 * 64 + n] = Wc1[15 * 64 + n];
        wf[F32_CV + 1 * 64 + n] = Wc1[16 * 64 + n];
        wf[F32_CV + 2 * 64 + n] = Wc1[17 * 64 + n];
        wf[F32_CV + 3 * 64 + n] = Wc1[18 * 64 + n];
        float cc = bc1[n];
        for (int c = 0; c < 15; ++c) cc += b2[1 + c] * Wc1[c * 64 + n];
        wf[F32_CV + 4 * 64 + n] = cc;
        if (lane < 16) wf[F32_BC2 + lane] = (lane < 12) ? bc2[lane >> 2] * LOG2E : 0.f;
        if (lane == 0) wf[F32_S0] = b2[0] * LOG2E + LOG2_LOG2E;
    }
}

// ---------------------------------------------------------------------------
// render: fully register-resident MLP pipeline, 8 t-segments per block.
// launch_bounds min-waves 4 (VGPR cap 128): allocator lands 60 arch-VGPR;
// min=8 caused catastrophic spill (VGPR=32, 1.3 GB scratch, 332 us).
// STRUCTURAL CEILING NOTE: true unified VGPR+AGPR usage ~120-124/wave
// (accumulators h/dh/t/rr4/cv/b2v share the gfx950 unified file) -> HW tier
// caps at 4 waves/SIMD no matter the grid (observed occupancy 27-33% across
// all configs). Render plateaued 40.5-41.5us across 5 variants; neither
// VALU (~55%) nor MFMA (~30%) pipe saturated -> latency-bound at the
// occupancy tier. unroll 2 was neutral (R9); fusion variants all regress.
// ---------------------------------------------------------------------------
__global__ __launch_bounds__(512, 4)
void render_kernel(const float* __restrict__ rays_o, const float* __restrict__ rays_d,
                   const float* __restrict__ tnoise, const float* __restrict__ aabb,
                   const void* __restrict__ ws, float* __restrict__ out) {
    __shared__ float sComb[WAVES][RPW][4];   // [0]=trans_end, [1..3]=rgb acc

    const int tid  = threadIdx.x;
    const int wv   = tid >> 6;
    const int lane = tid & 63;
    const int m    = lane & 15;       // ray within block / sample col
    const int q    = lane >> 4;       // quad
    const int r    = blockIdx.x * RPW + m;

    // weight fragments -> registers (40 VGPRs)
    const half8* wsv  = (const half8*)ws;
    const half4* w2v  = (const half4*)((const _Float16*)ws + H_W2K16);
    const half4* wc2v = (const half4*)((const _Float16*)ws + H_WC2K16);
    const half4* wc1v = (const half4*)((const _Float16*)ws + H_WC1K16);
    const float* wsf  = (const float*)ws;
    half8 fW1[4];
    half4 fW2[4], fWc1[4], fWc2[4];
    #pragma unroll
    for (int i = 0; i < 4; ++i) fW1[i]  = wsv[H8_W1 + i * 64 + lane];
    #pragma unroll
    for (int i = 0; i < 4; ++i) fW2[i]  = w2v[i * 64 + lane];
    #pragma unroll
    for (int i = 0; i < 4; ++i) fWc1[i] = wc1v[i * 64 + lane];
    #pragma unroll
    for (int i = 0; i < 4; ++i) fWc2[i] = wc2v[i * 64 + lane];
    const float4_ binit = ((const float4_*)(wsf + F32_BC2))[q];

    // per-ray setup
    float o0 = rays_o[r * 3 + 0], o1 = rays_o[r * 3 + 1], o2 = rays_o[r * 3 + 2];
    float d0 = rays_d[r * 3 + 0], d1 = rays_d[r * 3 + 1], d2 = rays_d[r * 3 + 2];
    float a00 = aabb[0], a01 = aabb[1], a02 = aabb[2];
    float a10 = aabb[3], a11 = aabb[4], a12 = aabb[5];

    float i0 = 1.0f / d0, i1 = 1.0f / d1, i2 = 1.0f / d2;
    float u0 = (a00 - o0) * i0, v0 = (a10 - o0) * i0;
    float u1 = (a01 - o1) * i1, v1 = (a11 - o1) * i1;
    float u2 = (a02 - o2) * i2, v2 = (a12 - o2) * i2;
    float tnear = fmaxf(fmaxf(fmaxf(fminf(u0, v0), fminf(u1, v1)), fminf(u2, v2)), 0.0f);
    float tfar  = fminf(fminf(fmaxf(u0, v0), fmaxf(u1, v1)), fmaxf(u2, v2));
    bool active = (tfar > tnear);
    float dt = tfar - tnear;
    float dt128 = dt * (1.0f / 128.0f);

    float dn  = sqrtf(d0 * d0 + d1 * d1 + d2 * d2);
    float idn = 1.0f / dn;
    // sigma bias in log2 domain, with log2(dn) folded in
    const float s0r = wsf[F32_S0] + __builtin_amdgcn_logf(dn);
    const float c0sh = 0.28209479177387814f;
    const float c1sh = 0.4886025119029199f;
    float y1 = c1sh * d1 * idn, y2 = c1sh * d2 * idn, y3 = c1sh * d0 * idn;

    // C1 C-initializer (per-ray): cv[n] = cconst[n] + c0*W15[n] + y.W16..18[n]
    float4_ cv[4];
    #pragma unroll
    for (int tau = 0; tau < 4; ++tau) {
        #pragma unroll
        for (int reg = 0; reg < 4; ++reg) {
            int n = tau * 16 + 4 * q + reg;
            float c = wsf[F32_CV + 4 * 64 + n];
            c = fmaf(c0sh, wsf[F32_CV + 0 * 64 + n], c);
            c = fmaf(y1,   wsf[F32_CV + 1 * 64 + n], c);
            c = fmaf(y2,   wsf[F32_CV + 2 * 64 + n], c);
            c = fmaf(y3,   wsf[F32_CV + 3 * 64 + n], c);
            cv[tau][reg] = c;
        }
    }

    // xn in revolutions domain, ray-affine prefolded: xr = ts*k + b
    float qs = 0.5f * (float)(1 << q);
    float sc0 = 2.0f / (a10 - a00), of0 = -a00 * sc0 - 1.0f;
    float sc1 = 2.0f / (a11 - a01), of1 = -a01 * sc1 - 1.0f;
    float sc2 = 2.0f / (a12 - a02), of2 = -a02 * sc2 - 1.0f;
    float kq0 = d0 * (sc0 * qs), bq0 = fmaf(o0, sc0 * qs, of0 * qs);
    float kq1 = d1 * (sc1 * qs), bq1 = fmaf(o1, sc1 * qs, of1 * qs);
    float kq2 = d2 * (sc2 * qs), bq2 = fmaf(o2, sc2 * qs, of2 * qs);

    const float4_ z4 = {0.f, 0.f, 0.f, 0.f};
    const bool q0 = (q == 0), q1 = (q == 1);
    const float c6 = q0 ? 2.0f : (q1 ? 1.0f : 0.0f);
    // e7 = fma(xr1, c7a, c7b): 2*xr1 on q0, const 1 on q1, 0 elsewhere
    const float c7a = q0 ? 2.0f : 0.0f;
    const float c7b = q1 ? 1.0f : 0.0f;

    float trans = 1.0f;
    float cacc = 0.0f;     // this lane's channel accumulator (q<3 meaningful)

    const int tbase = wv * TSEG;
    float nA = tnoise[(tbase + 0) * N_RAYS + r];
    float nB = tnoise[(tbase + 1) * N_RAYS + r];

    #pragma unroll 1
    for (int tt = 0; tt < TSEG; tt += 2) {
        const int t0 = tbase + tt, t1 = t0 + 1;
        // clamped prefetch: the clamp only hits samples whose value is dead
        int ic = t0 + 2; if (ic > T_STEPS - 1) ic = T_STEPS - 1;
        int id = t0 + 3; if (id > T_STEPS - 1) id = T_STEPS - 1;
        float nC = tnoise[ic * N_RAYS + r];
        float nD = tnoise[id * N_RAYS + r];
        float ts0 = fmaf((float)t0 + nA, dt128, tnear);
        float ts1 = fmaf((float)t1 + nB, dt128, tnear);
        float ts2 = fmaf((float)(t0 + 2) + nC, dt128, tnear);
        float tsP[2] = {ts0, ts1};
        float deltaP[2];
        deltaP[0] = ts1 - ts0;
        deltaP[1] = (t1 < T_STEPS - 1) ? (ts2 - ts1) : fmaf(tfar, 10.0f, -ts1);
        nA = nC; nB = nD;

        float dhx[2];      // sigma logit (log2 domain), broadcast to ALL lanes
        float4_ rgbP[2];   // reg0 = this quad's channel logit (log2 domain)

        // ---- per-phase fully in-register MLP: posenc -> L1 -> L2 -> C1 -> C2
        #pragma unroll
        for (int p = 0; p < 2; ++p) {
            float xr0 = fmaf(tsP[p], kq0, bq0);
            float xr1 = fmaf(tsP[p], kq1, bq1);
            float xr2 = fmaf(tsP[p], kq2, bq2);
            float s0 = __builtin_amdgcn_sinf(xr0);
            float s1 = __builtin_amdgcn_sinf(xr1);
            float s2 = __builtin_amdgcn_sinf(xr2);
            float cA = __builtin_amdgcn_cosf(xr0);
            float cB = __builtin_amdgcn_cosf(xr1);
            float cC = __builtin_amdgcn_cosf(xr2);
            float e6 = c6 * (q0 ? xr0 : xr2);
            float e7 = fmaf(xr1, c7a, c7b);
            union { uint32_t u[4]; half8 h; } xf_;
            xf_.u[0] = pk(s0, s1); xf_.u[1] = pk(s2, cA);
            xf_.u[2] = pk(cB, cC); xf_.u[3] = pk(e6, e7);
            half8 xf = xf_.h;

            // L1: 64 hidden x 16 rays, K=32 (enc padded)
            float4_ h0 = __builtin_amdgcn_mfma_f32_16x16x32_f16(fW1[0], xf, z4, 0, 0, 0);
            float4_ h1 = __builtin_amdgcn_mfma_f32_16x16x32_f16(fW1[1], xf, z4, 0, 0, 0);
            float4_ h2 = __builtin_amdgcn_mfma_f32_16x16x32_f16(fW1[2], xf, z4, 0, 0, 0);
            float4_ h3 = __builtin_amdgcn_mfma_f32_16x16x32_f16(fW1[3], xf, z4, 0, 0, 0);

            // relu-pack each h C-frag; C rows 4q+reg == K16 B-frag k=4q+j
            union { uint32_t u[2]; half4 h; } hb0_, hb1_, hb2_, hb3_;
            hb0_.u[0] = pkr(h0.x, h0.y); hb0_.u[1] = pkr(h0.z, h0.w);
            hb1_.u[0] = pkr(h1.x, h1.y); hb1_.u[1] = pkr(h1.z, h1.w);
            hb2_.u[0] = pkr(h2.x, h2.y); hb2_.u[1] = pkr(h2.z, h2.w);
            hb3_.u[0] = pkr(h3.x, h3.y); hb3_.u[1] = pkr(h3.z, h3.w);

            // L2: dh = sum_tau W2_tau . relu(h_tau); single accumulator chain
            float4_ dh = __builtin_amdgcn_mfma_f32_16x16x16f16(fW2[0], hb0_.h, z4, 0, 0, 0);
            dh = __builtin_amdgcn_mfma_f32_16x16x16f16(fW2[1], hb1_.h, dh, 0, 0, 0);
            dh = __builtin_amdgcn_mfma_f32_16x16x16f16(fW2[2], hb2_.h, dh, 0, 0, 0);
            dh = __builtin_amdgcn_mfma_f32_16x16x16f16(fW2[3], hb3_.h, dh, 0, 0, 0);

            // broadcast sigma logit (row 0, lives on lane (0,m)) to all lanes;
            // issued here so the bpermute latency hides under C1/C2 MFMAs
            dhx[p] = __shfl(dh.x, m, 64);

            // dh C-layout == 16x16x16 B-layout: feed C1 directly
            union { uint32_t u[2]; half4 h; } fb_;
            fb_.u[0] = pk(dh.x, dh.y); fb_.u[1] = pk(dh.z, dh.w);
            half4 fb = fb_.h;

            float4_ t0v = __builtin_amdgcn_mfma_f32_16x16x16f16(fWc1[0], fb, cv[0], 0, 0, 0);
            float4_ t1v = __builtin_amdgcn_mfma_f32_16x16x16f16(fWc1[1], fb, cv[1], 0, 0, 0);
            float4_ t2v = __builtin_amdgcn_mfma_f32_16x16x16f16(fWc1[2], fb, cv[2], 0, 0, 0);
            float4_ t3v = __builtin_amdgcn_mfma_f32_16x16x16f16(fWc1[3], fb, cv[3], 0, 0, 0);

            // relu-pack HC C-frags; feed C2 as 4 K=16 tiles, single acc chain
            union { uint32_t u[2]; half4 h; } cb0_, cb1_, cb2_, cb3_;
            cb0_.u[0] = pkr(t0v.x, t0v.y); cb0_.u[1] = pkr(t0v.z, t0v.w);
            cb1_.u[0] = pkr(t1v.x, t1v.y); cb1_.u[1] = pkr(t1v.z, t1v.w);
            cb2_.u[0] = pkr(t2v.x, t2v.y); cb2_.u[1] = pkr(t2v.z, t2v.w);
            cb3_.u[0] = pkr(t3v.x, t3v.y); cb3_.u[1] = pkr(t3v.z, t3v.w);

            float4_ rr4 = __builtin_amdgcn_mfma_f32_16x16x16f16(fWc2[0], cb0_.h, binit, 0, 0, 0);
            rr4 = __builtin_amdgcn_mfma_f32_16x16x16f16(fWc2[1], cb1_.h, rr4, 0, 0, 0);
            rr4 = __builtin_amdgcn_mfma_f32_16x16x16f16(fWc2[2], cb2_.h, rr4, 0, 0, 0);
            rr4 = __builtin_amdgcn_mfma_f32_16x16x16f16(fWc2[3], cb3_.h, rr4, 0, 0, 0);
            rgbP[p] = rr4;
        }

        // ---- TAIL: wave-uniform scan, exp2-domain, 2-op telescoped update ----
        #pragma unroll
        for (int p = 0; p < 2; ++p) {
            float sg = __builtin_amdgcn_exp2f(dhx[p] + s0r);   // log2e*dn*sigma
            float sd = sg * deltaP[p];
            float e  = __builtin_amdgcn_exp2f(-sd);
            float s  = __builtin_amdgcn_rcpf(1.0f + __builtin_amdgcn_exp2f(-rgbP[p].x));
            float tn = trans * e;
            cacc = fmaf(trans - tn, s, cacc);
            trans = tn;
        }
    }

    if (q == 3) sComb[wv][m][0] = trans;       // trans uniform across quads
    else        sComb[wv][m][1 + q] = cacc;
    __syncthreads();

    // cross-segment combine: pure multiply chain, alpha_map telescopes
    if (tid < RPW) {
        float P = 1.0f, C0 = 0.0f, C1 = 0.0f, C2 = 0.0f;
        #pragma unroll
        for (int s = 0; s < WAVES; ++s) {
            C0 = fmaf(P, sComb[s][tid][1], C0);
            C1 = fmaf(P, sComb[s][tid][2], C1);
            C2 = fmaf(P, sComb[s][tid][3], C2);
            P *= sComb[s][tid][0];
        }
        float act = active ? 1.0f : 0.0f;
        const int rg = blockIdx.x * RPW + tid;
        out[rg * 4 + 0] = C0 * act;
        out[rg * 4 + 1] = C1 * act;
        out[rg * 4 + 2] = C2 * act;
        out[rg * 4 + 3] = (1.0f - P) * act;
    }
}

extern "C" void kernel_launch(void* const* d_in, const int* in_sizes, int n_in,
                              void* d_out, int out_size, void* d_ws, size_t ws_size,
                              hipStream_t stream) {
    const float* rays_o = (const float*)d_in[0];
    const float* rays_d = (const float*)d_in[1];
    const float* tnoise = (const float*)d_in[2];
    const float* aabb   = (const float*)d_in[3];
    const float* W1  = (const float*)d_in[4];
    const float* b1  = (const float*)d_in[5];
    const float* W2  = (const float*)d_in[6];
    const float* b2  = (const float*)d_in[7];
    const float* Wc1 = (const float*)d_in[8];
    const float* bc1 = (const float*)d_in[9];
    const float* Wc2 = (const float*)d_in[10];
    const float* bc2 = (const float*)d_in[11];

    prep_weights<<<dim3(17), dim3(64), 0, stream>>>(W1, b1, W2, b2, Wc1, bc1, Wc2, bc2, d_ws);

    dim3 grid(N_RAYS / RPW);   // 1024 blocks
    dim3 block(WAVES * 64);    // 512 threads, 8 waves
    render_kernel<<<grid, block, 0, stream>>>(rays_o, rays_d, tnoise, aabb, d_ws,
                                              (float*)d_out);
}